// Round 3
// baseline (3544.946 us; speedup 1.0000x reference)
//
#include <hip/hip_runtime.h>

typedef unsigned short u16;
typedef __attribute__((ext_vector_type(4))) float f32x4;
typedef __attribute__((ext_vector_type(8))) short bf16x8;
#define MFMA16(a,b,c) __builtin_amdgcn_mfma_f32_16x16x32_bf16((a),(b),(c),0,0,0)

__device__ __forceinline__ u16 f2bf(float f){
  unsigned int u = __float_as_uint(f);
  u += 0x7FFFu + ((u >> 16) & 1u);
  return (u16)(u >> 16);
}
__device__ __forceinline__ float bf2f(u16 h){
  return __uint_as_float(((unsigned int)h) << 16);
}

#if defined(__has_builtin)
#  if __has_builtin(__builtin_amdgcn_cvt_pk_bf16_f32)
#    define PK_BF16 1
#  endif
#endif
__device__ __forceinline__ unsigned int pack_bf(float a, float b){
#ifdef PK_BF16
  auto v = __builtin_amdgcn_cvt_pk_bf16_f32(a, b);
  return __builtin_bit_cast(unsigned int, v);
#else
  return (unsigned int)f2bf(a) | ((unsigned int)f2bf(b) << 16);
#endif
}

// fast gates: exp2-based, no clamps (saturate correctly at +-inf)
__device__ __forceinline__ float fsig(float x){
  float e = __builtin_amdgcn_exp2f(-1.44269504f * x);
  return __builtin_amdgcn_rcpf(1.f + e);
}
__device__ __forceinline__ float ftanh(float x){
  float e = __builtin_amdgcn_exp2f(2.88539008f * x);
  return 1.f - 2.f * __builtin_amdgcn_rcpf(1.f + e);
}

__device__ __forceinline__ float sigmoid_f(float x){
  x = fminf(fmaxf(x, -30.f), 30.f);
  return __fdividef(1.f, 1.f + __expf(-x));
}
__device__ __forceinline__ float tanh_f(float x){
  x = fminf(fmaxf(x, -15.f), 15.f);
  float e = __expf(-2.f * x);
  return __fdividef(1.f - e, 1.f + e);
}

// fp32 -> bf16 weight conversion (grid-stride)
__global__ void cvt_bf16_kernel(const float* __restrict__ in, u16* __restrict__ out, int n){
  int i = blockIdx.x * 256 + threadIdx.x;
  int stride = gridDim.x * 256;
  for (; i < n; i += stride) out[i] = f2bf(in[i]);
}

// Block-wide LN stats for R rows of a [R x 256] LDS buffer (stride 256).
template<int R>
__device__ __forceinline__ void ln_stats_rows(const float* __restrict__ O,
                                              float* __restrict__ mean_s,
                                              float* __restrict__ rstd_s){
  const int tid  = threadIdx.x;
  const int wave = tid >> 6, lane = tid & 63;
  constexpr int RW = R / 4;
  #pragma unroll
  for (int rr = 0; rr < RW; rr++){
    const int r = wave * RW + rr;
    float s = 0.f, q = 0.f;
    #pragma unroll
    for (int i = lane; i < 256; i += 64){ float v = O[r*256 + i]; s += v; q += v*v; }
    #pragma unroll
    for (int off = 32; off; off >>= 1){ s += __shfl_down(s, off); q += __shfl_down(q, off); }
    if (lane == 0){
      float m   = s * (1.f/256.f);
      float var = q * (1.f/256.f) - m*m;
      mean_s[r] = m;
      rstd_s[r] = rsqrtf(fmaxf(var, 0.f) + 1e-5f);
    }
  }
}

// ---------------------------------------------------------------------------
// GRU + phi SLNN + scatter, round 3:
//  - TM edges/block (64 for E0, 32 for E1), wave w owns cols [64w,64w+64)
//  - k-chunk-major LDS layout [g][e][8] -> conflict-free ds_read_b128 A-frags
//  - h recurrence value + running mean kept in registers (bf16-packed hprev)
//  - gate biases folded into MFMA accumulator init; exp2-based gates
//  - quarter-split (one 16-col group at a time) to bound VGPR; clobber stops CSE
// ---------------------------------------------------------------------------
template<int TM, int DIN, int NFD>
__global__ __launch_bounds__(256, 2)
void gru_mfma2_kernel(int E,
    const float* __restrict__ x,        // [E, 8, DIN] fp32
    const float* __restrict__ nodef,    // [*, NFD] fp32
    const int*   __restrict__ src,
    const int*   __restrict__ dst,
    const float* __restrict__ hist,     // [*, 256] fp32
    const u16*   __restrict__ Wih,      // [768, DIN] bf16
    const u16*   __restrict__ Whh,      // [768, 256] bf16
    const float* __restrict__ bih,
    const float* __restrict__ bhh,
    const u16*   __restrict__ phiW,     // [256, NFD+256] bf16
    const float* __restrict__ phib,
    const float* __restrict__ phig,
    const float* __restrict__ phibeta,
    float* __restrict__ delta)          // [*, 256] fp32, pre-zeroed
{
  constexpr int MT = TM / 16;           // M-tiles (4 or 2)
  constexpr int KP = NFD + 256;         // phi K
  constexpr int HB = TM * 256;          // elems per h buffer (g-major [32][TM][8])

  __shared__ u16  hb[2 * HB];           // double-buffered h (bf16); after loop:
                                        //   hb[0..HB) = emb, hb[HB..) = nodef stage
  __shared__ u16  xl[TM * DIN];         // x_t stage (g-major)
  __shared__ float sums_s[4 * TM], sqs_s[4 * TM];
  __shared__ float mean_s[TM], rstd_s[TM];
  __shared__ int   srcs_s[TM], dsts_s[TM];

  const int tid  = threadIdx.x;
  const int wave = tid >> 6, lane = tid & 63;
  const int quad = lane >> 4, ln15 = lane & 15;
  const int cbase = wave * 64;
  const int e0   = blockIdx.x * TM;

  if (tid < TM){
    int e = e0 + tid;
    int ec = (e < E) ? e : (E - 1);
    srcs_s[tid] = src[ec];
    dsts_s[tid] = dst[ec];
  }

  float brc[4], bzc[4], bnic[4], bnhc[4];
  #pragma unroll
  for (int nt = 0; nt < 4; nt++){
    int c = cbase + nt * 16 + ln15;
    brc[nt]  = bih[c]       + bhh[c];
    bzc[nt]  = bih[256 + c] + bhh[256 + c];
    bnic[nt] = bih[512 + c];
    bnhc[nt] = bhh[512 + c];
  }

  const int qoff = quad * 8;

  // x staging assignment: TPR threads per edge-row, CPT floats each
  constexpr int TPR = 256 / TM;
  constexpr int CPT = DIN / TPR;
  const int srow   = tid / TPR;
  const int schunk = (tid - srow * TPR) * CPT;
  const float* xrowp = x + (size_t)((e0 + srow < E) ? (e0 + srow) : (E - 1)) * (8 * DIN) + schunk;

  float4 xr[CPT / 4];
  #pragma unroll
  for (int i = 0; i < CPT / 4; i++) xr[i] = *(const float4*)(xrowp + i * 4);

  f32x4 hs[4][MT];                       // fp32 running sum of h (for mean)
  unsigned int hprev[4][MT][2];          // bf16-packed h (recurrence value)
  #pragma unroll
  for (int nt = 0; nt < 4; nt++)
    #pragma unroll
    for (int mt = 0; mt < MT; mt++){
      hs[nt][mt] = (f32x4){0.f,0.f,0.f,0.f};
      hprev[nt][mt][0] = 0u; hprev[nt][mt][1] = 0u;
    }

  #pragma unroll 1
  for (int t = 0; t < 8; t++){
    __syncthreads();                     // (A) xl WAR + h_{t-1} writes visible
    #pragma unroll
    for (int i = 0; i < CPT / 8; i++){
      uint4 w;
      w.x = pack_bf(xr[2*i].x,   xr[2*i].y);
      w.y = pack_bf(xr[2*i].z,   xr[2*i].w);
      w.z = pack_bf(xr[2*i+1].x, xr[2*i+1].y);
      w.w = pack_bf(xr[2*i+1].z, xr[2*i+1].w);
      *(uint4*)(xl + ((schunk/8 + i) * TM + srow) * 8) = w;
    }
    __syncthreads();                     // (B) xl visible

    const u16* rd = hb + ((t + 1) & 1) * HB;
    u16*       wr = hb + (t & 1) * HB;

    #pragma unroll
    for (int nt = 0; nt < 4; nt++){
      const int c = cbase + nt * 16 + ln15;
      f32x4 aR  = {brc[nt],  brc[nt],  brc[nt],  brc[nt]};
      f32x4 aZ  = {bzc[nt],  bzc[nt],  bzc[nt],  bzc[nt]};
      f32x4 aNI = {bnic[nt], bnic[nt], bnic[nt], bnic[nt]};
      f32x4 aNH = {bnhc[nt], bnhc[nt], bnhc[nt], bnhc[nt]};
      f32x4 accR[MT], accZ[MT], accNI[MT], accNH[MT];
      #pragma unroll
      for (int mt = 0; mt < MT; mt++){ accR[mt]=aR; accZ[mt]=aZ; accNI[mt]=aNI; accNH[mt]=aNH; }

      if (t > 0){
        #pragma unroll
        for (int kt = 0; kt < 8; kt++){
          bf16x8 a[MT];
          #pragma unroll
          for (int mt = 0; mt < MT; mt++)
            a[mt] = *(const bf16x8*)(rd + ((kt*4 + quad) * TM + mt*16 + ln15) * 8);
          const u16* bp = Whh + (size_t)c * 256 + kt * 32 + qoff;
          bf16x8 br = *(const bf16x8*)(bp);
          bf16x8 bz = *(const bf16x8*)(bp + 256 * 256);
          bf16x8 bn = *(const bf16x8*)(bp + 512 * 256);
          #pragma unroll
          for (int mt = 0; mt < MT; mt++){
            accR[mt]  = MFMA16(a[mt], br, accR[mt]);
            accZ[mt]  = MFMA16(a[mt], bz, accZ[mt]);
            accNH[mt] = MFMA16(a[mt], bn, accNH[mt]);
          }
        }
      }
      #pragma unroll
      for (int kt = 0; kt < DIN / 32; kt++){
        bf16x8 a[MT];
        #pragma unroll
        for (int mt = 0; mt < MT; mt++)
          a[mt] = *(const bf16x8*)(xl + ((kt*4 + quad) * TM + mt*16 + ln15) * 8);
        const u16* up = Wih + (size_t)c * DIN + kt * 32 + qoff;
        bf16x8 ur = *(const bf16x8*)(up);
        bf16x8 uz = *(const bf16x8*)(up + 256 * DIN);
        bf16x8 un = *(const bf16x8*)(up + 512 * DIN);
        #pragma unroll
        for (int mt = 0; mt < MT; mt++){
          accR[mt]  = MFMA16(a[mt], ur, accR[mt]);
          accZ[mt]  = MFMA16(a[mt], uz, accZ[mt]);
          accNI[mt] = MFMA16(a[mt], un, accNI[mt]);
        }
      }

      // gates + h update for this 16-col group
      #pragma unroll
      for (int mt = 0; mt < MT; mt++){
        const int wbase = ((c >> 3) * TM + mt*16 + quad*4) * 8 + (c & 7);
        #pragma unroll
        for (int p = 0; p < 2; p++){
          float h0 = bf2f((u16)(hprev[nt][mt][p]));
          float h1 = bf2f((u16)(hprev[nt][mt][p] >> 16));
          float r0 = fsig(accR[mt][2*p]),   r1 = fsig(accR[mt][2*p+1]);
          float z0 = fsig(accZ[mt][2*p]),   z1 = fsig(accZ[mt][2*p+1]);
          float n0 = ftanh(accNI[mt][2*p]   + r0 * accNH[mt][2*p]);
          float n1 = ftanh(accNI[mt][2*p+1] + r1 * accNH[mt][2*p+1]);
          float hn0 = n0 + z0 * (h0 - n0);
          float hn1 = n1 + z1 * (h1 - n1);
          hs[nt][mt][2*p]   += hn0;
          hs[nt][mt][2*p+1] += hn1;
          unsigned int pk = pack_bf(hn0, hn1);
          hprev[nt][mt][p] = pk;
          if (t < 7){
            wr[wbase + (2*p)   * 8] = (u16)pk;
            wr[wbase + (2*p+1) * 8] = (u16)(pk >> 16);
          }
        }
      }
      asm volatile("" ::: "memory");   // keep quarters independent (no A-frag CSE)
    }

    // prefetch x_{t+1} LAST (younger than all weight loads -> no FIFO coupling)
    if (t < 7){
      const float* xp = xrowp + (t + 1) * DIN;
      #pragma unroll
      for (int i = 0; i < CPT / 4; i++) xr[i] = *(const float4*)(xp + i * 4);
    }
  }

  __syncthreads();   // all t=7 A-frag reads of hb[0] done

  // emb = mean(h) -> hb[0] (g-major); nodef[src] -> hb[HB..] (g-major)
  {
    u16* eb = hb;
    #pragma unroll
    for (int nt = 0; nt < 4; nt++){
      const int c = cbase + nt * 16 + ln15;
      #pragma unroll
      for (int mt = 0; mt < MT; mt++){
        const int base = ((c >> 3) * TM + mt*16 + quad*4) * 8 + (c & 7);
        #pragma unroll
        for (int q = 0; q < 4; q++)
          eb[base + q * 8] = f2bf(hs[nt][mt][q] * 0.125f);
      }
    }
    u16* nb = hb + HB;
    constexpr int NCPT = NFD / TPR;
    const int nrow   = tid / TPR;
    const int nchunk = (tid - nrow * TPR) * NCPT;
    const float* np = nodef + (size_t)srcs_s[nrow] * NFD + nchunk;
    #pragma unroll
    for (int i = 0; i < NCPT / 8; i++){
      float4 va = *(const float4*)(np + i * 8);
      float4 vb = *(const float4*)(np + i * 8 + 4);
      uint4 w;
      w.x = pack_bf(va.x, va.y); w.y = pack_bf(va.z, va.w);
      w.z = pack_bf(vb.x, vb.y); w.w = pack_bf(vb.z, vb.w);
      *(uint4*)(nb + ((nchunk/8 + i) * TM + nrow) * 8) = w;
    }
  }
  __syncthreads();

  float pb[4], gg[4], gb[4];
  #pragma unroll
  for (int nt = 0; nt < 4; nt++){
    int c = cbase + nt * 16 + ln15;
    pb[nt] = phib[c]; gg[nt] = phig[c]; gb[nt] = phibeta[c];
  }

  // phi GEMM: K = NFD (nodef in hb[HB..]) + 256 (emb in hb[0..])
  f32x4 P[4][MT];
  #pragma unroll
  for (int nt = 0; nt < 4; nt++)
    #pragma unroll
    for (int mt = 0; mt < MT; mt++)
      P[nt][mt] = (f32x4){pb[nt], pb[nt], pb[nt], pb[nt]};

  #pragma unroll
  for (int nt = 0; nt < 4; nt++){
    const int c = cbase + nt * 16 + ln15;
    #pragma unroll
    for (int kt = 0; kt < NFD / 32; kt++){
      bf16x8 a[MT];
      #pragma unroll
      for (int mt = 0; mt < MT; mt++)
        a[mt] = *(const bf16x8*)(hb + HB + ((kt*4 + quad) * TM + mt*16 + ln15) * 8);
      bf16x8 b = *(const bf16x8*)(phiW + (size_t)c * KP + kt * 32 + qoff);
      #pragma unroll
      for (int mt = 0; mt < MT; mt++) P[nt][mt] = MFMA16(a[mt], b, P[nt][mt]);
    }
    #pragma unroll
    for (int kt = 0; kt < 8; kt++){
      bf16x8 a[MT];
      #pragma unroll
      for (int mt = 0; mt < MT; mt++)
        a[mt] = *(const bf16x8*)(hb + ((kt*4 + quad) * TM + mt*16 + ln15) * 8);
      bf16x8 b = *(const bf16x8*)(phiW + (size_t)c * KP + NFD + kt * 32 + qoff);
      #pragma unroll
      for (int mt = 0; mt < MT; mt++) P[nt][mt] = MFMA16(a[mt], b, P[nt][mt]);
    }
    asm volatile("" ::: "memory");
  }

  // LN stats (bias already in P): per-row shuffle reduce then cross-wave via LDS
  float sl[MT][4], sq[MT][4];
  #pragma unroll
  for (int mt = 0; mt < MT; mt++)
    #pragma unroll
    for (int q = 0; q < 4; q++){ sl[mt][q] = 0.f; sq[mt][q] = 0.f; }
  #pragma unroll
  for (int nt = 0; nt < 4; nt++)
    #pragma unroll
    for (int mt = 0; mt < MT; mt++)
      #pragma unroll
      for (int q = 0; q < 4; q++){
        float v = P[nt][mt][q];
        sl[mt][q] += v; sq[mt][q] += v * v;
      }
  #pragma unroll
  for (int off = 1; off < 16; off <<= 1){
    #pragma unroll
    for (int mt = 0; mt < MT; mt++)
      #pragma unroll
      for (int q = 0; q < 4; q++){
        sl[mt][q] += __shfl_xor(sl[mt][q], off);
        sq[mt][q] += __shfl_xor(sq[mt][q], off);
      }
  }
  if (ln15 == 0){
    #pragma unroll
    for (int mt = 0; mt < MT; mt++)
      #pragma unroll
      for (int q = 0; q < 4; q++){
        int row = mt*16 + quad*4 + q;
        sums_s[wave * TM + row] = sl[mt][q];
        sqs_s[wave * TM + row]  = sq[mt][q];
      }
  }
  __syncthreads();
  if (tid < TM){
    float m = 0.f, qq = 0.f;
    #pragma unroll
    for (int w = 0; w < 4; w++){ m += sums_s[w * TM + tid]; qq += sqs_s[w * TM + tid]; }
    m  *= (1.f / 256.f);
    qq *= (1.f / 256.f);
    mean_s[tid] = m;
    rstd_s[tid] = rsqrtf(fmaxf(qq - m * m, 0.f) + 1e-5f);
  }
  __syncthreads();

  // y = relu(LN(P)); msg = relu(y - hist[src]) -> atomic scatter to delta[dst]
  #pragma unroll
  for (int nt = 0; nt < 4; nt++){
    const int c = cbase + nt * 16 + ln15;
    #pragma unroll
    for (int mt = 0; mt < MT; mt++){
      #pragma unroll
      for (int q = 0; q < 4; q++){
        const int e  = mt*16 + quad*4 + q;
        const int ge = e0 + e;
        float y = (P[nt][mt][q] - mean_s[e]) * rstd_s[e] * gg[nt] + gb[nt];
        y = fmaxf(y, 0.f);
        float mv = y - hist[(size_t)srcs_s[e] * 256 + c];
        if (ge < E && mv > 0.f)
          atomicAdd(delta + (size_t)dsts_s[e] * 256 + c, mv);
      }
    }
  }
}

// ---------------------------------------------------------------------------
// self-SLNN: out = relu(LN(feat[nid] @ W[:, WS-K:].T + b)); optional
// out2 = out - hist[nid].
// ---------------------------------------------------------------------------
template<int K, int WS>
__global__ __launch_bounds__(256)
void self_slnn_kernel(int N,
    const float* __restrict__ feat,
    const int*   __restrict__ nid,
    const float* __restrict__ W,
    const float* __restrict__ b,
    const float* __restrict__ g,
    const float* __restrict__ beta,
    const float* __restrict__ hist,
    float* __restrict__ out,
    float* __restrict__ out2)
{
  constexpr int R = 8;
  __shared__ float X[R*K];
  __shared__ float O[R*256];
  __shared__ float mean_s[R], rstd_s[R];
  __shared__ int   nids[R];
  const int tid = threadIdx.x;
  const int n0  = blockIdx.x * R;
  if (tid < R) nids[tid] = (n0 + tid < N) ? nid[n0 + tid] : 0;
  __syncthreads();
  for (int i = tid; i < R*K; i += 256){
    int r = i / K, k = i - r*K;
    X[i] = feat[(size_t)nids[r]*K + k];
  }
  __syncthreads();
  const int c = tid;
  const float* Wc = W + (size_t)c*WS + (WS - K);
  float acc[R];
  const float bc0 = b[c];
  #pragma unroll
  for (int r = 0; r < R; r++) acc[r] = bc0;
  #pragma unroll 1
  for (int k = 0; k < K; k += 4){
    float4 w = *(const float4*)(Wc + k);
    #pragma unroll
    for (int r = 0; r < R; r++){
      float4 xv = *(const float4*)(X + r*K + k);
      acc[r] += w.x*xv.x + w.y*xv.y + w.z*xv.z + w.w*xv.w;
    }
  }
  #pragma unroll
  for (int r = 0; r < R; r++) O[r*256 + c] = acc[r];
  __syncthreads();
  ln_stats_rows<R>(O, mean_s, rstd_s);
  __syncthreads();
  const float gc = g[c], bc = beta[c];
  #pragma unroll
  for (int r = 0; r < R; r++){
    int n = n0 + r;
    if (n < N){
      float y = fmaxf((acc[r] - mean_s[r]) * rstd_s[r] * gc + bc, 0.f);
      out[(size_t)n*256 + c] = y;
      if (out2) out2[(size_t)n*256 + c] = y - hist[(size_t)nids[r]*256 + c];
    }
  }
}

// ---------------------------------------------------------------------------
// compose-SLNN: X = [ (delta - selfA)*subg (+ agg*normv) | selfB ]  (K=512)
// ---------------------------------------------------------------------------
__global__ __launch_bounds__(256)
void compose_slnn_kernel(int N,
    const float* __restrict__ delta,
    const float* __restrict__ selfA,
    const float* __restrict__ selfB,
    const float* __restrict__ subg,
    const float* __restrict__ agg,
    const float* __restrict__ normv,
    const float* __restrict__ W,     // [256, 512]
    const float* __restrict__ b,
    const float* __restrict__ g,
    const float* __restrict__ beta,
    float* __restrict__ out)
{
  constexpr int R = 8;
  __shared__ float X[R*512];
  __shared__ float O[R*256];
  __shared__ float mean_s[R], rstd_s[R];
  const int tid = threadIdx.x;
  const int n0  = blockIdx.x * R;
  for (int i = tid; i < R*512; i += 256){
    int r = i >> 9, k = i & 511;
    int n = n0 + r;
    float v = 0.f;
    if (n < N){
      if (k < 256){
        v = (delta[(size_t)n*256 + k] - selfA[(size_t)n*256 + k]) * subg[n];
        if (agg) v += agg[(size_t)n*256 + k] * normv[n];
      } else {
        v = selfB[(size_t)n*256 + (k - 256)];
      }
    }
    X[i] = v;
  }
  __syncthreads();
  const int c = tid;
  const float* Wc = W + (size_t)c*512;
  float acc[R];
  const float bc0 = b[c];
  #pragma unroll
  for (int r = 0; r < R; r++) acc[r] = bc0;
  #pragma unroll 1
  for (int k = 0; k < 512; k += 4){
    float4 w = *(const float4*)(Wc + k);
    #pragma unroll
    for (int r = 0; r < R; r++){
      float4 xv = *(const float4*)(X + r*512 + k);
      acc[r] += w.x*xv.x + w.y*xv.y + w.z*xv.z + w.w*xv.w;
    }
  }
  #pragma unroll
  for (int r = 0; r < R; r++) O[r*256 + c] = acc[r];
  __syncthreads();
  ln_stats_rows<R>(O, mean_s, rstd_s);
  __syncthreads();
  const float gc = g[c], bc = beta[c];
  #pragma unroll
  for (int r = 0; r < R; r++){
    int n = n0 + r;
    if (n < N)
      out[(size_t)n*256 + c] = fmaxf((acc[r] - mean_s[r]) * rstd_s[r] * gc + bc, 0.f);
  }
}

// ---------------------------------------------------------------------------
// readout: logit = (h2 @ fc1.T + b1) @ fc2.T + b2
// ---------------------------------------------------------------------------
__global__ __launch_bounds__(256)
void readout_kernel(int N,
    const float* __restrict__ h2,
    const float* __restrict__ W1,  // [512, 256]
    const float* __restrict__ b1,
    const float* __restrict__ W2,  // [16, 512]
    const float* __restrict__ b2,
    float* __restrict__ out)
{
  constexpr int R = 8;
  __shared__ float X[R*256];
  __shared__ float T[R*512];
  const int tid = threadIdx.x;
  const int n0  = blockIdx.x * R;
  for (int i = tid; i < R*256; i += 256){
    int r = i >> 8, k = i & 255;
    int n = n0 + r;
    X[i] = (n < N) ? h2[(size_t)n*256 + k] : 0.f;
  }
  __syncthreads();
  const int c = tid;
  const float* Wa = W1 + (size_t)c*256;
  const float* Wb = W1 + (size_t)(c+256)*256;
  float acca[R], accb[R];
  const float ba = b1[c], bb = b1[c+256];
  #pragma unroll
  for (int r = 0; r < R; r++){ acca[r] = ba; accb[r] = bb; }
  #pragma unroll 1
  for (int k = 0; k < 256; k += 4){
    float4 wa = *(const float4*)(Wa + k);
    float4 wb = *(const float4*)(Wb + k);
    #pragma unroll
    for (int r = 0; r < R; r++){
      float4 xv = *(const float4*)(X + r*256 + k);
      acca[r] += wa.x*xv.x + wa.y*xv.y + wa.z*xv.z + wa.w*xv.w;
      accb[r] += wb.x*xv.x + wb.y*xv.y + wb.z*xv.z + wb.w*xv.w;
    }
  }
  #pragma unroll
  for (int r = 0; r < R; r++){ T[r*512 + c] = acca[r]; T[r*512 + 256 + c] = accb[r]; }
  __syncthreads();
  if (tid < R*16){
    int r = tid >> 4, o = tid & 15;
    int n = n0 + r;
    if (n < N){
      float s = b2[o];
      const float* w  = W2 + (size_t)o*512;
      const float* tr = T + r*512;
      #pragma unroll 4
      for (int k = 0; k < 512; k++) s += tr[k]*w[k];
      out[(size_t)n*16 + o] = s;
    }
  }
}

// ---------------------------------------------------------------------------
extern "C" void kernel_launch(void* const* d_in, const int* in_sizes, int n_in,
                              void* d_out, int out_size, void* d_ws, size_t ws_size,
                              hipStream_t stream) {
  const float* nf     = (const float*)d_in[0];
  const float* x0     = (const float*)d_in[1];
  const float* x1     = (const float*)d_in[2];
  const float* hist0  = (const float*)d_in[3];
  const float* hist1  = (const float*)d_in[4];
  const float* aggh1  = (const float*)d_in[5];
  const float* subg1  = (const float*)d_in[6];
  const float* subg2  = (const float*)d_in[7];
  const float* norm2  = (const float*)d_in[8];
  const int*   src0   = (const int*)d_in[9];
  const int*   dst0   = (const int*)d_in[10];
  const int*   src1   = (const int*)d_in[11];
  const int*   dst1   = (const int*)d_in[12];
  const int*   nid0   = (const int*)d_in[13];
  const int*   nid1   = (const int*)d_in[14];
  const float* g0Wih  = (const float*)d_in[15];
  const float* g0Whh  = (const float*)d_in[16];
  const float* g0bih  = (const float*)d_in[17];
  const float* g0bhh  = (const float*)d_in[18];
  const float* g1Wih  = (const float*)d_in[19];
  const float* g1Whh  = (const float*)d_in[20];
  const float* g1bih  = (const float*)d_in[21];
  const float* g1bhh  = (const float*)d_in[22];
  const float* phi0W  = (const float*)d_in[23];
  const float* phi0b  = (const float*)d_in[24];
  const float* phi0g  = (const float*)d_in[25];
  const float* phi0be = (const float*)d_in[26];
  const float* phi1W  = (const float*)d_in[27];
  const float* phi1b  = (const float*)d_in[28];
  const float* phi1g  = (const float*)d_in[29];
  const float* phi1be = (const float*)d_in[30];
  const float* nu0W   = (const float*)d_in[31];
  const float* nu0b   = (const float*)d_in[32];
  const float* nu0g   = (const float*)d_in[33];
  const float* nu0be  = (const float*)d_in[34];
  const float* nu1W   = (const float*)d_in[35];
  const float* nu1b   = (const float*)d_in[36];
  const float* nu1g   = (const float*)d_in[37];
  const float* nu1be  = (const float*)d_in[38];
  const float* fc1W   = (const float*)d_in[39];
  const float* fc1b   = (const float*)d_in[40];
  const float* fc2W   = (const float*)d_in[41];
  const float* fc2b   = (const float*)d_in[42];

  const int E0 = in_sizes[9];
  const int E1 = in_sizes[11];
  const int N1 = in_sizes[13];
  const int N2 = in_sizes[14];

  float* ws     = (float*)d_ws;
  float* delta0 = ws;
  float* selfh0 = delta0 + (size_t)N1*256;
  float* h1p    = selfh0 + (size_t)N1*256;
  float* delta1 = h1p    + (size_t)N1*256;
  float* selfh1 = delta1 + (size_t)N2*256;
  float* selfd1 = selfh1 + (size_t)N2*256;
  float* h2p    = selfd1 + (size_t)N2*256;

  u16* wbf       = (u16*)(h2p + (size_t)N2*256);
  u16* g0Wih_bf  = wbf;
  u16* g0Whh_bf  = g0Wih_bf + 768*64;
  u16* phi0W_bf  = g0Whh_bf + 768*256;
  u16* g1Wih_bf  = phi0W_bf + 256*384;
  u16* g1Whh_bf  = g1Wih_bf + 768*256;
  u16* phi1W_bf  = g1Whh_bf + 768*256;

  hipMemsetAsync(delta0, 0, (size_t)N1*256*sizeof(float), stream);
  hipMemsetAsync(delta1, 0, (size_t)N2*256*sizeof(float), stream);

  cvt_bf16_kernel<<<192, 256, 0, stream>>>(g0Wih, g0Wih_bf, 768*64);
  cvt_bf16_kernel<<<768, 256, 0, stream>>>(g0Whh, g0Whh_bf, 768*256);
  cvt_bf16_kernel<<<384, 256, 0, stream>>>(phi0W, phi0W_bf, 256*384);
  cvt_bf16_kernel<<<768, 256, 0, stream>>>(g1Wih, g1Wih_bf, 768*256);
  cvt_bf16_kernel<<<768, 256, 0, stream>>>(g1Whh, g1Whh_bf, 768*256);
  cvt_bf16_kernel<<<512, 256, 0, stream>>>(phi1W, phi1W_bf, 256*512);

  const int gN1 = (N1 + 7) / 8;
  const int gN2 = (N2 + 7) / 8;

  // ---- layer 0 ----
  self_slnn_kernel<128, 384><<<gN1, 256, 0, stream>>>(
      N1, nf, nid0, phi0W, phi0b, phi0g, phi0be, nullptr, selfh0, nullptr);

  gru_mfma2_kernel<64, 64, 128><<<(E0 + 63) / 64, 256, 0, stream>>>(
      E0, x0, nf, src0, dst0, hist0,
      g0Wih_bf, g0Whh_bf, g0bih, g0bhh,
      phi0W_bf, phi0b, phi0g, phi0be, delta0);

  compose_slnn_kernel<<<gN1, 256, 0, stream>>>(
      N1, delta0, selfh0, selfh0, subg1, nullptr, nullptr,
      nu0W, nu0b, nu0g, nu0be, h1p);

  // ---- layer 1 ----
  self_slnn_kernel<256, 512><<<gN2, 256, 0, stream>>>(
      N2, h1p, nid1, phi1W, phi1b, phi1g, phi1be, hist1, selfh1, selfd1);

  gru_mfma2_kernel<32, 256, 256><<<(E1 + 31) / 32, 256, 0, stream>>>(
      E1, x1, h1p, src1, dst1, hist1,
      g1Wih_bf, g1Whh_bf, g1bih, g1bhh,
      phi1W_bf, phi1b, phi1g, phi1be, delta1);

  compose_slnn_kernel<<<gN2, 256, 0, stream>>>(
      N2, delta1, selfd1, selfh1, subg2, aggh1, norm2,
      nu1W, nu1b, nu1g, nu1be, h2p);

  // ---- readout ----
  readout_kernel<<<gN2, 256, 0, stream>>>(
      N2, h2p, fc1W, fc1b, fc2W, fc2b, (float*)d_out);

  (void)n_in; (void)out_size; (void)ws_size;
}